// Round 11
// baseline (98.857 us; speedup 1.0000x reference)
//
#include <hip/hip_runtime.h>
#include <stdint.h>

typedef __attribute__((ext_vector_type(8))) short short8;
typedef __attribute__((ext_vector_type(8))) signed char schar8;
typedef __attribute__((ext_vector_type(4))) float f32x4;

__device__ __forceinline__ unsigned short f2bf(float f) {
  union { float f; uint32_t u; } v; v.f = f;
  uint32_t u = v.u;
  uint32_t r = (u + 0x7FFFu + ((u >> 16) & 1u)) >> 16;
  return (unsigned short)r;
}
__device__ __forceinline__ float bf2f(unsigned short h) {
  union { uint32_t u; float f; } v; v.u = ((uint32_t)h) << 16; return v.f;
}

// ============================================================================
// Phase 1 (TRANSPOSED): D[chan][node] = W1^T · x^T, so each 16-lane group
// {l15, l15+16, l15+32, l15+48} holds ALL 128 channels of node l15 (32 each)
// -> per-node absmax is 31 local fmax + 2 shfl_xor, NO cross-wave LDS, and
// the tile keeps R6's proven 2-barrier shape. W1^T lives in REGISTERS
// (afrag[8][4], loaded once per block); only 4 ds_read_b128/wave/tile.
// Channel permutation phys = lg*32 + m*4 + reg makes each lane's 32 int8
// outputs contiguous -> 2x16B coalesced stores. Bias applied in edge phase.
// ============================================================================
#define NBM 64
__global__ __launch_bounds__(256, 2)
void node_phase_q8(const float* __restrict__ src_emb,
                   const float* __restrict__ dst_emb,
                   const float* __restrict__ W1,
                   int8_t* __restrict__ Q,
                   float* __restrict__ SC,
                   int Nn, int ntiles) {
  __shared__ __align__(16) char Als[NBM * 256];   // 16 KB: 64 nodes x 128 bf16

  const int tbl = blockIdx.y;
  const float* emb = tbl ? dst_emb : src_emb;
  const float* Wt  = W1 + (size_t)tbl * 128 * 128;
  int8_t* Qt  = Q  + (size_t)tbl * Nn * 128;
  float*  SCt = SC + (size_t)tbl * Nn;

  const int tid  = threadIdx.x;
  const int lane = tid & 63;
  const int w    = tid >> 6;           // wave w -> nodes [w*16, w*16+16) of tile
  const int l15  = lane & 15;
  const int lg   = lane >> 4;          // 0..3

  // ---- A-frags: afrag[m][s] holds W1^T rows (channels) for m-block m.
  //      A[row=chan][k]: lane l15 = row-in-block, k-slice = s*32 + lg*8 + j.
  //      Permuted: phys channel of logical row r in block m = (r>>2)*32+m*4+(r&3).
  const int pbase = (l15 >> 2) * 32 + (l15 & 3);
  short8 afrag[8][4];
#pragma unroll
  for (int m = 0; m < 8; ++m) {
#pragma unroll
    for (int s = 0; s < 4; ++s) {
      short8 t;
#pragma unroll
      for (int j = 0; j < 8; ++j) {
        const int k = s * 32 + lg * 8 + j;
        t[j] = (short)f2bf(Wt[(size_t)k * 128 + pbase + m * 4]);
      }
      afrag[m][s] = t;
    }
  }

  const int q = tid & 15, r0 = tid >> 4;
  const int gx = gridDim.x;

  // ---- prefetch first tile into registers ----
  float4 p0[4], p1[4];
#pragma unroll
  for (int i = 0; i < 4; ++i) {
    const int node = blockIdx.x * NBM + i * 16 + r0;
    if (node < Nn) {
      const float* base = emb + (size_t)node * 128 + q * 8;
      p0[i] = *(const float4*)base;
      p1[i] = *(const float4*)(base + 4);
    }
  }

  for (int t = blockIdx.x; t < ntiles; t += gx) {
    const int t0 = t * NBM;

    // ---- prefetched regs -> swizzled LDS (rows = nodes) ----
#pragma unroll
    for (int i = 0; i < 4; ++i) {
      const int row = i * 16 + r0;
      short8 hv;
      hv[0] = (short)f2bf(p0[i].x); hv[1] = (short)f2bf(p0[i].y);
      hv[2] = (short)f2bf(p0[i].z); hv[3] = (short)f2bf(p0[i].w);
      hv[4] = (short)f2bf(p1[i].x); hv[5] = (short)f2bf(p1[i].y);
      hv[6] = (short)f2bf(p1[i].z); hv[7] = (short)f2bf(p1[i].w);
      const int byteoff = row * 256 + ((q * 16) ^ ((row & 7) << 4));
      *(short8*)(Als + byteoff) = hv;
    }
    __syncthreads();

    // ---- issue next tile's gathers (latency hides under compute) ----
    const int tn = t + gx;
    if (tn < ntiles) {
#pragma unroll
      for (int i = 0; i < 4; ++i) {
        const int node = tn * NBM + i * 16 + r0;
        if (node < Nn) {
          const float* base = emb + (size_t)node * 128 + q * 8;
          p0[i] = *(const float4*)base;
          p1[i] = *(const float4*)(base + 4);
        }
      }
    }

    // ---- MFMA: B-operand = x^T (col = node = l15), 4 ds_reads total ----
    f32x4 acc[8];
#pragma unroll
    for (int m = 0; m < 8; ++m) acc[m] = (f32x4){0.f, 0.f, 0.f, 0.f};

    const int brow = w * 16 + l15;                 // node row in LDS
    const int bswz = (l15 & 7) << 4;
#pragma unroll
    for (int s = 0; s < 4; ++s) {
      const int boff = brow * 256 + ((s * 64 + lg * 16) ^ bswz);
      const short8 b = *(const short8*)(Als + boff);
#pragma unroll
      for (int m = 0; m < 8; ++m)
        acc[m] = __builtin_amdgcn_mfma_f32_16x16x32_bf16(afrag[m][s], b, acc[m], 0, 0, 0);
    }

    // ---- wave-local per-node absmax -> quantize -> 2x16B coalesced stores --
    float am = 1e-20f;
#pragma unroll
    for (int m = 0; m < 8; ++m)
#pragma unroll
      for (int reg = 0; reg < 4; ++reg)
        am = fmaxf(am, fabsf(acc[m][reg]));
    am = fmaxf(am, __shfl_xor(am, 16));
    am = fmaxf(am, __shfl_xor(am, 32));

    const int node = t0 + w * 16 + l15;
    if (node < Nn) {
      const float rq = 127.0f / am;
      uint32_t d[8];
#pragma unroll
      for (int m = 0; m < 8; ++m) {
        uint32_t pk = 0;
#pragma unroll
        for (int reg = 0; reg < 4; ++reg)
          pk |= ((uint32_t)((int)rintf(acc[m][reg] * rq) & 255)) << (8 * reg);
        d[m] = pk;
      }
      uint4 lo; lo.x = d[0]; lo.y = d[1]; lo.z = d[2]; lo.w = d[3];
      uint4 hi; hi.x = d[4]; hi.y = d[5]; hi.z = d[6]; hi.w = d[7];
      int8_t* dst = Qt + (size_t)node * 128 + lg * 32;
      *(uint4*)dst        = lo;
      *(uint4*)(dst + 16) = hi;
      if (lg == 0) SCt[node] = am * (1.0f / 127.0f);
    }
    __syncthreads();
  }
}

// ============================================================================
// Phase 2: out[e] = sigmoid( sum_c relu(su*qu[c] + sv*qv[c] + b1[c]) * W2[c] + b2 )
// 16 lanes/edge, 8 int8 channels/lane (8B row-load). Bias applied here.
// ============================================================================
__global__ __launch_bounds__(256, 8)
void edge_phase_q8(const int8_t* __restrict__ Qu,
                   const int8_t* __restrict__ Qv,
                   const float* __restrict__ scu,
                   const float* __restrict__ scv,
                   const int* __restrict__ eidx,
                   const float* __restrict__ b1,
                   const float* __restrict__ W2,
                   const float* __restrict__ b2,
                   float* __restrict__ out,
                   int E) {
  const int tid = threadIdx.x;
  const int l15 = tid & 15;
  const int sg  = tid >> 4;

  float w2s[8], b1s[8];
#pragma unroll
  for (int j = 0; j < 8; ++j) {
    w2s[j] = W2[l15 * 8 + j];
    b1s[j] = b1[l15 * 8 + j];
  }
  const float b2s = b2[0];
  const int stride = gridDim.x * 16;

#pragma unroll 2
  for (int e = blockIdx.x * 16 + sg; e < E; e += stride) {
    const int s = eidx[e];
    const int d = eidx[E + e];
    const schar8 qu = *(const schar8*)(Qu + (size_t)s * 128 + l15 * 8);
    const schar8 qv = *(const schar8*)(Qv + (size_t)d * 128 + l15 * 8);
    const float su = scu[s];
    const float sv = scv[d];
    float acc = 0.f;
#pragma unroll
    for (int j = 0; j < 8; ++j) {
      float g = fmaf((float)(int)qu[j], su,
                fmaf((float)(int)qv[j], sv, b1s[j]));
      g = g > 0.f ? g : 0.f;
      acc = fmaf(g, w2s[j], acc);
    }
    acc += __shfl_xor(acc, 1, 16);
    acc += __shfl_xor(acc, 2, 16);
    acc += __shfl_xor(acc, 4, 16);
    acc += __shfl_xor(acc, 8, 16);
    if (l15 == 0) out[e] = 1.f / (1.f + __expf(-(acc + b2s)));
  }
}

// ============================================================================
// Fallback (proven R2 kernel): fused gather+MFMA, used if ws_size too small.
// ============================================================================
#define BM 64
__global__ __launch_bounds__(256, 4)
void edge_decoder_fused(const float* __restrict__ src_emb,
                        const float* __restrict__ dst_emb,
                        const int* __restrict__ eidx,
                        const float* __restrict__ W1,
                        const float* __restrict__ b1,
                        const float* __restrict__ W2,
                        const float* __restrict__ b2,
                        float* __restrict__ out,
                        int E, int ntiles) {
  __shared__ __align__(16) char Als[BM * 512];
  __shared__ float rowpart[4][BM];

  const int tid  = threadIdx.x;
  const int lane = tid & 63;
  const int w    = tid >> 6;
  const int l15  = lane & 15;
  const int lk8  = (lane >> 4) * 8;

  short8 bfrag[8][2];
#pragma unroll
  for (int s = 0; s < 8; ++s) {
#pragma unroll
    for (int nf = 0; nf < 2; ++nf) {
      const int col = w * 32 + nf * 16 + l15;
      short8 t;
#pragma unroll
      for (int j = 0; j < 8; ++j) {
        const int k = s * 32 + lk8 + j;
        t[j] = (short)f2bf(W1[k * 128 + col]);
      }
      bfrag[s][nf] = t;
    }
  }
  float b1v[2], w2v[2];
#pragma unroll
  for (int nf = 0; nf < 2; ++nf) {
    const int col = w * 32 + nf * 16 + l15;
    b1v[nf] = b1[col];
    w2v[nf] = W2[col];
  }
  const float b2s = b2[0];

  const int q  = tid & 31;
  const int r0 = tid >> 5;
  const int qq = q & 15;
  const bool is_src = (q < 16);
  const int swz = (l15 & 7) << 4;

  for (int t = blockIdx.x; t < ntiles; t += gridDim.x) {
    const int t0 = t * BM;
#pragma unroll
    for (int i = 0; i < 8; ++i) {
      const int row = i * 8 + r0;
      const int e = t0 + row;
      if (e < E) {
        const int node = is_src ? eidx[e] : eidx[E + e];
        const float* base = (is_src ? src_emb : dst_emb) + (size_t)node * 128 + qq * 8;
        const float4 f0 = *(const float4*)base;
        const float4 f1 = *(const float4*)(base + 4);
        short8 hv;
        hv[0] = (short)f2bf(f0.x); hv[1] = (short)f2bf(f0.y);
        hv[2] = (short)f2bf(f0.z); hv[3] = (short)f2bf(f0.w);
        hv[4] = (short)f2bf(f1.x); hv[5] = (short)f2bf(f1.y);
        hv[6] = (short)f2bf(f1.z); hv[7] = (short)f2bf(f1.w);
        const int byteoff = row * 512 + ((q * 16) ^ ((row & 7) << 4));
        *(short8*)(Als + byteoff) = hv;
      }
    }
    __syncthreads();

    for (int m = 0; m < 4; ++m) {
      f32x4 acc0 = {0.f, 0.f, 0.f, 0.f};
      f32x4 acc1 = {0.f, 0.f, 0.f, 0.f};
      const int rowb = (m * 16 + l15) * 512;
      const int kb0  = lk8 * 2;
#pragma unroll
      for (int s = 0; s < 8; ++s) {
        const int off = rowb + ((s * 64 + kb0) ^ swz);
        const short8 a = *(const short8*)(Als + off);
        acc0 = __builtin_amdgcn_mfma_f32_16x16x32_bf16(a, bfrag[s][0], acc0, 0, 0, 0);
        acc1 = __builtin_amdgcn_mfma_f32_16x16x32_bf16(a, bfrag[s][1], acc1, 0, 0, 0);
      }
      float pr[4];
#pragma unroll
      for (int reg = 0; reg < 4; ++reg) {
        float h0 = acc0[reg] + b1v[0]; h0 = h0 > 0.f ? h0 : 0.f;
        float h1 = acc1[reg] + b1v[1]; h1 = h1 > 0.f ? h1 : 0.f;
        pr[reg] = h0 * w2v[0] + h1 * w2v[1];
      }
#pragma unroll
      for (int off = 1; off < 16; off <<= 1) {
#pragma unroll
        for (int reg = 0; reg < 4; ++reg)
          pr[reg] += __shfl_xor(pr[reg], off, 64);
      }
      if (l15 == 0) {
        const int rbase = m * 16 + (lane >> 4) * 4;
#pragma unroll
        for (int reg = 0; reg < 4; ++reg)
          rowpart[w][rbase + reg] = pr[reg];
      }
    }
    __syncthreads();

    if (tid < BM) {
      const int e = t0 + tid;
      if (e < E) {
        const float sum = rowpart[0][tid] + rowpart[1][tid] +
                          rowpart[2][tid] + rowpart[3][tid] + b2s;
        out[e] = 1.f / (1.f + __expf(-sum));
      }
    }
    __syncthreads();
  }
}

extern "C" void kernel_launch(void* const* d_in, const int* in_sizes, int n_in,
                              void* d_out, int out_size, void* d_ws, size_t ws_size,
                              hipStream_t stream) {
  const float* src = (const float*)d_in[0];
  const float* dst = (const float*)d_in[1];
  const int*   eix = (const int*)d_in[2];
  const float* W1  = (const float*)d_in[3];
  const float* b1  = (const float*)d_in[4];
  const float* W2  = (const float*)d_in[5];
  const float* b2  = (const float*)d_in[6];
  float* out = (float*)d_out;

  const int E  = in_sizes[2] / 2;
  const int Nn = in_sizes[0] / 128;
  // ws layout: Q (2 tables x Nn x 128 int8) | SC (2 tables x Nn f32)
  const size_t q_bytes  = (size_t)2 * Nn * 128;
  const size_t sc_bytes = (size_t)2 * Nn * sizeof(float);

  if (ws_size >= q_bytes + sc_bytes) {
    int8_t* Q  = (int8_t*)d_ws;
    float*  SC = (float*)((char*)d_ws + q_bytes);
    const int ntiles_n = (Nn + NBM - 1) / NBM;
    const int gx = ntiles_n < 256 ? ntiles_n : 256;   // 512 blocks = 2/CU (VGPR-limited)
    node_phase_q8<<<dim3(gx, 2), 256, 0, stream>>>(src, dst, W1, Q, SC, Nn, ntiles_n);
    const int nchunks = (E + 15) / 16;
    const int nblk = nchunks < 2048 ? nchunks : 2048;
    edge_phase_q8<<<nblk, 256, 0, stream>>>(Q, Q + (size_t)Nn * 128, SC, SC + Nn,
                                            eix, b1, W2, b2, out, E);
  } else {
    const int ntiles = (E + BM - 1) / BM;
    const int grid = ntiles < 2048 ? ntiles : 2048;
    edge_decoder_fused<<<grid, 256, 0, stream>>>(src, dst, eix, W1, b1, W2, b2,
                                                 out, E, ntiles);
  }
}

// Round 12
// 74.233 us; speedup vs baseline: 1.3317x; 1.3317x over previous
//
#include <hip/hip_runtime.h>
#include <stdint.h>

typedef __attribute__((ext_vector_type(8))) short short8;
typedef __attribute__((ext_vector_type(8))) signed char schar8;
typedef __attribute__((ext_vector_type(4))) float f32x4;

__device__ __forceinline__ unsigned short f2bf(float f) {
  union { float f; uint32_t u; } v; v.f = f;
  uint32_t u = v.u;
  uint32_t r = (u + 0x7FFFu + ((u >> 16) & 1u)) >> 16;
  return (unsigned short)r;
}
__device__ __forceinline__ float bf2f(unsigned short h) {
  union { uint32_t u; float f; } v; v.u = ((uint32_t)h) << 16; return v.f;
}

// ============================================================================
// Phase 1 (R6-proven, ~25us): U[i] = bf16(src_emb[i] @ W1[:128] + b1);
// V[j] = bf16(dst_emb[j] @ W1[128:]). Grid-stride 64-row tiles; register
// prefetch pipeline; adjacent-col B layout -> packed dword C stores.
// ============================================================================
#define NBM 64
__global__ __launch_bounds__(256, 4)
void node_phase_bf16(const float* __restrict__ src_emb,
                     const float* __restrict__ dst_emb,
                     const float* __restrict__ W1,
                     const float* __restrict__ b1,
                     unsigned short* __restrict__ UV,
                     int Nn, int ntiles) {
  __shared__ __align__(16) char Als[NBM * 256];   // 16 KB

  const int tbl = blockIdx.y;
  const float* emb = tbl ? dst_emb : src_emb;
  const float* Wt  = W1 + (size_t)tbl * 128 * 128;
  unsigned short* outp = UV + (size_t)tbl * Nn * 128;

  const int tid  = threadIdx.x;
  const int lane = tid & 63;
  const int w    = tid >> 6;
  const int l15  = lane & 15;
  const int lk8  = (lane >> 4) * 8;

  short8 bfrag[4][2];
#pragma unroll
  for (int s = 0; s < 4; ++s) {
#pragma unroll
    for (int nf = 0; nf < 2; ++nf) {
      const int col = w * 32 + 2 * l15 + nf;
      short8 t;
#pragma unroll
      for (int j = 0; j < 8; ++j) {
        const int k = s * 32 + lk8 + j;
        t[j] = (short)f2bf(Wt[k * 128 + col]);
      }
      bfrag[s][nf] = t;
    }
  }
  const int colb = w * 32 + 2 * l15;
  const float bias0 = tbl ? 0.f : b1[colb];
  const float bias1 = tbl ? 0.f : b1[colb + 1];

  const int q = tid & 15, r0 = tid >> 4;
  const int swz = (l15 & 7) << 4;
  const int gx = gridDim.x;

  float4 p0[4], p1[4];
#pragma unroll
  for (int i = 0; i < 4; ++i) {
    const int node = blockIdx.x * NBM + i * 16 + r0;
    if (node < Nn) {
      const float* base = emb + (size_t)node * 128 + q * 8;
      p0[i] = *(const float4*)base;
      p1[i] = *(const float4*)(base + 4);
    }
  }

  for (int t = blockIdx.x; t < ntiles; t += gx) {
    const int t0 = t * NBM;

#pragma unroll
    for (int i = 0; i < 4; ++i) {
      const int row = i * 16 + r0;
      short8 hv;
      hv[0] = (short)f2bf(p0[i].x); hv[1] = (short)f2bf(p0[i].y);
      hv[2] = (short)f2bf(p0[i].z); hv[3] = (short)f2bf(p0[i].w);
      hv[4] = (short)f2bf(p1[i].x); hv[5] = (short)f2bf(p1[i].y);
      hv[6] = (short)f2bf(p1[i].z); hv[7] = (short)f2bf(p1[i].w);
      const int byteoff = row * 256 + ((q * 16) ^ ((row & 7) << 4));
      *(short8*)(Als + byteoff) = hv;
    }
    __syncthreads();

    const int tn = t + gx;
    if (tn < ntiles) {
#pragma unroll
      for (int i = 0; i < 4; ++i) {
        const int node = tn * NBM + i * 16 + r0;
        if (node < Nn) {
          const float* base = emb + (size_t)node * 128 + q * 8;
          p0[i] = *(const float4*)base;
          p1[i] = *(const float4*)(base + 4);
        }
      }
    }

#pragma unroll
    for (int m = 0; m < 4; ++m) {
      f32x4 acc0 = {0.f, 0.f, 0.f, 0.f};
      f32x4 acc1 = {0.f, 0.f, 0.f, 0.f};
      const int rowb = (m * 16 + l15) * 256;
      const int kb0  = lk8 * 2;
#pragma unroll
      for (int s = 0; s < 4; ++s) {
        const int off = rowb + ((s * 64 + kb0) ^ swz);
        const short8 a = *(const short8*)(Als + off);
        acc0 = __builtin_amdgcn_mfma_f32_16x16x32_bf16(a, bfrag[s][0], acc0, 0, 0, 0);
        acc1 = __builtin_amdgcn_mfma_f32_16x16x32_bf16(a, bfrag[s][1], acc1, 0, 0, 0);
      }
#pragma unroll
      for (int reg = 0; reg < 4; ++reg) {
        const int orow = t0 + m * 16 + ((lane >> 4) * 4) + reg;
        if (orow < Nn) {
          const uint32_t pk = (uint32_t)f2bf(acc0[reg] + bias0) |
                              ((uint32_t)f2bf(acc1[reg] + bias1) << 16);
          *(uint32_t*)&outp[(size_t)orow * 128 + colb] = pk;
        }
      }
    }
    __syncthreads();
  }
}

// ============================================================================
// Phase 1.5 (NEW, streaming ~15us): per-row int8 quantization of UV.
// 16 lanes per row (128 bf16 = 16 x short8); absmax via 4 shfl_xor; TLP
// hides the VALU chain (the R9 lesson: never put this on a GEMM wave's
// critical path). Q[r][c] = rint(h*127/amax), SC[r] = amax/127.
// ============================================================================
__global__ __launch_bounds__(256, 8)
void quant_rows_q8(const unsigned short* __restrict__ UV,
                   int8_t* __restrict__ Q,
                   float* __restrict__ SC,
                   int nrows) {
  const int tid = threadIdx.x;
  const int l15 = tid & 15;
  const int stride = gridDim.x * 16;

  for (int r = blockIdx.x * 16 + (tid >> 4); r < nrows; r += stride) {
    const short8 v = *(const short8*)(UV + (size_t)r * 128 + l15 * 8);
    float f[8];
    float am = 1e-20f;
#pragma unroll
    for (int j = 0; j < 8; ++j) {
      f[j] = bf2f((unsigned short)v[j]);
      am = fmaxf(am, fabsf(f[j]));
    }
    am = fmaxf(am, __shfl_xor(am, 1, 16));
    am = fmaxf(am, __shfl_xor(am, 2, 16));
    am = fmaxf(am, __shfl_xor(am, 4, 16));
    am = fmaxf(am, __shfl_xor(am, 8, 16));
    const float rq = 127.0f / am;
    uint32_t lo = 0, hi = 0;
#pragma unroll
    for (int j = 0; j < 4; ++j)
      lo |= ((uint32_t)((int)rintf(f[j] * rq) & 255)) << (8 * j);
#pragma unroll
    for (int j = 4; j < 8; ++j)
      hi |= ((uint32_t)((int)rintf(f[j] * rq) & 255)) << (8 * (j - 4));
    uint2 pk; pk.x = lo; pk.y = hi;
    *(uint2*)(Q + (size_t)r * 128 + l15 * 8) = pk;
    if (l15 == 0) SC[r] = am * (1.0f / 127.0f);
  }
}

// ============================================================================
// Phase 2 (R9-proven, ~24us): out[e] = sigmoid( sum_c relu(su*qu+sv*qv)*W2 + b2 )
// (bias already folded into U). 16 lanes/edge, 8 int8 channels/lane.
// ============================================================================
__global__ __launch_bounds__(256, 8)
void edge_phase_q8(const int8_t* __restrict__ Qu,
                   const int8_t* __restrict__ Qv,
                   const float* __restrict__ scu,
                   const float* __restrict__ scv,
                   const int* __restrict__ eidx,
                   const float* __restrict__ W2,
                   const float* __restrict__ b2,
                   float* __restrict__ out,
                   int E) {
  const int tid = threadIdx.x;
  const int l15 = tid & 15;
  const int sg  = tid >> 4;

  float w2s[8];
#pragma unroll
  for (int j = 0; j < 8; ++j) w2s[j] = W2[l15 * 8 + j];
  const float b2s = b2[0];
  const int stride = gridDim.x * 16;

#pragma unroll 2
  for (int e = blockIdx.x * 16 + sg; e < E; e += stride) {
    const int s = eidx[e];
    const int d = eidx[E + e];
    const schar8 qu = *(const schar8*)(Qu + (size_t)s * 128 + l15 * 8);
    const schar8 qv = *(const schar8*)(Qv + (size_t)d * 128 + l15 * 8);
    const float su = scu[s];
    const float sv = scv[d];
    float acc = 0.f;
#pragma unroll
    for (int j = 0; j < 8; ++j) {
      float g = (float)(int)qu[j] * su + (float)(int)qv[j] * sv;
      g = g > 0.f ? g : 0.f;
      acc = fmaf(g, w2s[j], acc);
    }
    acc += __shfl_xor(acc, 1, 16);
    acc += __shfl_xor(acc, 2, 16);
    acc += __shfl_xor(acc, 4, 16);
    acc += __shfl_xor(acc, 8, 16);
    if (l15 == 0) out[e] = 1.f / (1.f + __expf(-(acc + b2s)));
  }
}

// ============================================================================
// Mid-tier edge (R6-proven, 46us): bf16 gather-reduce, used if ws fits UV only.
// ============================================================================
__global__ __launch_bounds__(256, 8)
void edge_phase_bf16(const unsigned short* __restrict__ UV,
                     const int* __restrict__ eidx,
                     const float* __restrict__ W2,
                     const float* __restrict__ b2,
                     float* __restrict__ out,
                     int E, int Nn) {
  const int tid = threadIdx.x;
  const int l15 = tid & 15;
  const int sg  = tid >> 4;

  float w2s[8];
#pragma unroll
  for (int j = 0; j < 8; ++j) w2s[j] = W2[l15 * 8 + j];
  const float b2s = b2[0];
  const unsigned short* U = UV;
  const unsigned short* V = UV + (size_t)Nn * 128;
  const int stride = gridDim.x * 16;

#pragma unroll 2
  for (int e = blockIdx.x * 16 + sg; e < E; e += stride) {
    const int s = eidx[e];
    const int d = eidx[E + e];
    const short8 u8 = *(const short8*)(U + (size_t)s * 128 + l15 * 8);
    const short8 v8 = *(const short8*)(V + (size_t)d * 128 + l15 * 8);
    float acc = 0.f;
#pragma unroll
    for (int j = 0; j < 8; ++j) {
      float g = bf2f((unsigned short)u8[j]) + bf2f((unsigned short)v8[j]);
      g = g > 0.f ? g : 0.f;
      acc = fmaf(g, w2s[j], acc);
    }
    acc += __shfl_xor(acc, 1, 16);
    acc += __shfl_xor(acc, 2, 16);
    acc += __shfl_xor(acc, 4, 16);
    acc += __shfl_xor(acc, 8, 16);
    if (l15 == 0) out[e] = 1.f / (1.f + __expf(-(acc + b2s)));
  }
}

// ============================================================================
// Fallback (proven R2 kernel): fused gather+MFMA, used if ws too small.
// ============================================================================
#define BM 64
__global__ __launch_bounds__(256, 4)
void edge_decoder_fused(const float* __restrict__ src_emb,
                        const float* __restrict__ dst_emb,
                        const int* __restrict__ eidx,
                        const float* __restrict__ W1,
                        const float* __restrict__ b1,
                        const float* __restrict__ W2,
                        const float* __restrict__ b2,
                        float* __restrict__ out,
                        int E, int ntiles) {
  __shared__ __align__(16) char Als[BM * 512];
  __shared__ float rowpart[4][BM];

  const int tid  = threadIdx.x;
  const int lane = tid & 63;
  const int w    = tid >> 6;
  const int l15  = lane & 15;
  const int lk8  = (lane >> 4) * 8;

  short8 bfrag[8][2];
#pragma unroll
  for (int s = 0; s < 8; ++s) {
#pragma unroll
    for (int nf = 0; nf < 2; ++nf) {
      const int col = w * 32 + nf * 16 + l15;
      short8 t;
#pragma unroll
      for (int j = 0; j < 8; ++j) {
        const int k = s * 32 + lk8 + j;
        t[j] = (short)f2bf(W1[k * 128 + col]);
      }
      bfrag[s][nf] = t;
    }
  }
  float b1v[2], w2v[2];
#pragma unroll
  for (int nf = 0; nf < 2; ++nf) {
    const int col = w * 32 + nf * 16 + l15;
    b1v[nf] = b1[col];
    w2v[nf] = W2[col];
  }
  const float b2s = b2[0];

  const int q  = tid & 31;
  const int r0 = tid >> 5;
  const int qq = q & 15;
  const bool is_src = (q < 16);
  const int swz = (l15 & 7) << 4;

  for (int t = blockIdx.x; t < ntiles; t += gridDim.x) {
    const int t0 = t * BM;
#pragma unroll
    for (int i = 0; i < 8; ++i) {
      const int row = i * 8 + r0;
      const int e = t0 + row;
      if (e < E) {
        const int node = is_src ? eidx[e] : eidx[E + e];
        const float* base = (is_src ? src_emb : dst_emb) + (size_t)node * 128 + qq * 8;
        const float4 f0 = *(const float4*)base;
        const float4 f1 = *(const float4*)(base + 4);
        short8 hv;
        hv[0] = (short)f2bf(f0.x); hv[1] = (short)f2bf(f0.y);
        hv[2] = (short)f2bf(f0.z); hv[3] = (short)f2bf(f0.w);
        hv[4] = (short)f2bf(f1.x); hv[5] = (short)f2bf(f1.y);
        hv[6] = (short)f2bf(f1.z); hv[7] = (short)f2bf(f1.w);
        const int byteoff = row * 512 + ((q * 16) ^ ((row & 7) << 4));
        *(short8*)(Als + byteoff) = hv;
      }
    }
    __syncthreads();

    for (int m = 0; m < 4; ++m) {
      f32x4 acc0 = {0.f, 0.f, 0.f, 0.f};
      f32x4 acc1 = {0.f, 0.f, 0.f, 0.f};
      const int rowb = (m * 16 + l15) * 512;
      const int kb0  = lk8 * 2;
#pragma unroll
      for (int s = 0; s < 8; ++s) {
        const int off = rowb + ((s * 64 + kb0) ^ swz);
        const short8 a = *(const short8*)(Als + off);
        acc0 = __builtin_amdgcn_mfma_f32_16x16x32_bf16(a, bfrag[s][0], acc0, 0, 0, 0);
        acc1 = __builtin_amdgcn_mfma_f32_16x16x32_bf16(a, bfrag[s][1], acc1, 0, 0, 0);
      }
      float pr[4];
#pragma unroll
      for (int reg = 0; reg < 4; ++reg) {
        float h0 = acc0[reg] + b1v[0]; h0 = h0 > 0.f ? h0 : 0.f;
        float h1 = acc1[reg] + b1v[1]; h1 = h1 > 0.f ? h1 : 0.f;
        pr[reg] = h0 * w2v[0] + h1 * w2v[1];
      }
#pragma unroll
      for (int off = 1; off < 16; off <<= 1) {
#pragma unroll
        for (int reg = 0; reg < 4; ++reg)
          pr[reg] += __shfl_xor(pr[reg], off, 64);
      }
      if (l15 == 0) {
        const int rbase = m * 16 + (lane >> 4) * 4;
#pragma unroll
        for (int reg = 0; reg < 4; ++reg)
          rowpart[w][rbase + reg] = pr[reg];
      }
    }
    __syncthreads();

    if (tid < BM) {
      const int e = t0 + tid;
      if (e < E) {
        const float sum = rowpart[0][tid] + rowpart[1][tid] +
                          rowpart[2][tid] + rowpart[3][tid] + b2s;
        out[e] = 1.f / (1.f + __expf(-sum));
      }
    }
    __syncthreads();
  }
}

extern "C" void kernel_launch(void* const* d_in, const int* in_sizes, int n_in,
                              void* d_out, int out_size, void* d_ws, size_t ws_size,
                              hipStream_t stream) {
  const float* src = (const float*)d_in[0];
  const float* dst = (const float*)d_in[1];
  const int*   eix = (const int*)d_in[2];
  const float* W1  = (const float*)d_in[3];
  const float* b1  = (const float*)d_in[4];
  const float* W2  = (const float*)d_in[5];
  const float* b2  = (const float*)d_in[6];
  float* out = (float*)d_out;

  const int E  = in_sizes[2] / 2;
  const int Nn = in_sizes[0] / 128;
  const int nrows = 2 * Nn;
  // ws layout: UV bf16 (2*Nn*128*2B) | Q int8 (2*Nn*128) | SC f32 (2*Nn*4)
  const size_t uv_bytes = (size_t)nrows * 128 * 2;
  const size_t q_bytes  = (size_t)nrows * 128;
  const size_t sc_bytes = (size_t)nrows * sizeof(float);

  const int ntiles_n = (Nn + NBM - 1) / NBM;
  const int gx = ntiles_n < 512 ? ntiles_n : 512;
  const int nchunks = (E + 15) / 16;
  const int nblk = nchunks < 2048 ? nchunks : 2048;

  if (ws_size >= uv_bytes + q_bytes + sc_bytes) {
    unsigned short* UV = (unsigned short*)d_ws;
    int8_t* Q  = (int8_t*)((char*)d_ws + uv_bytes);
    float*  SC = (float*)((char*)d_ws + uv_bytes + q_bytes);
    node_phase_bf16<<<dim3(gx, 2), 256, 0, stream>>>(src, dst, W1, b1, UV, Nn, ntiles_n);
    const int qblk = ((nrows + 15) / 16) < 2048 ? ((nrows + 15) / 16) : 2048;
    quant_rows_q8<<<qblk, 256, 0, stream>>>(UV, Q, SC, nrows);
    edge_phase_q8<<<nblk, 256, 0, stream>>>(Q, Q + (size_t)Nn * 128, SC, SC + Nn,
                                            eix, W2, b2, out, E);
  } else if (ws_size >= uv_bytes) {
    unsigned short* UV = (unsigned short*)d_ws;
    node_phase_bf16<<<dim3(gx, 2), 256, 0, stream>>>(src, dst, W1, b1, UV, Nn, ntiles_n);
    edge_phase_bf16<<<nblk, 256, 0, stream>>>(UV, eix, W2, b2, out, E, Nn);
  } else {
    const int ntiles = (E + BM - 1) / BM;
    const int grid = ntiles < 2048 ? ntiles : 2048;
    edge_decoder_fused<<<grid, 256, 0, stream>>>(src, dst, eix, W1, b1, W2, b2,
                                                 out, E, ntiles);
  }
}